// Round 13
// baseline (287.675 us; speedup 1.0000x reference)
//
#include <hip/hip_runtime.h>

// ---------------------------------------------------------------------------
// TransformerBlock on MI355X (gfx950): bf16 MFMA pipeline
//   B=4 S=2048 D=768 H=12 hs=64 F=3072, M=B*S=8192
// Round 13: per-block fixed-cost attack. W2/Wo on new 128x64-tile gemm_n64
//           (768 blocks = 3/CU even, no quantization tail). W1 gets an
//           LDS-coalesced epilogue (16B stores). GEMM core = R9 proven
//           double-buffer + counted vmcnt(4). QKV V-fusion + tcastW kept.
// ---------------------------------------------------------------------------

typedef __attribute__((ext_vector_type(4))) float f32x4;
typedef __attribute__((ext_vector_type(8))) short bf16x8;   // 8 bf16 in 4 VGPRs
typedef __attribute__((ext_vector_type(4))) unsigned short u16x4;

#define GLB_AS __attribute__((address_space(1)))
#define LDS_AS __attribute__((address_space(3)))

__device__ __forceinline__ unsigned short f2bf(float f) {
  unsigned int u = __float_as_uint(f);
  u = (u + 0x7FFFu + ((u >> 16) & 1u)) >> 16;   // RNE
  return (unsigned short)u;
}

__device__ __forceinline__ void gload16(const void* g, void* l) {
  __builtin_amdgcn_global_load_lds((const GLB_AS unsigned int*)g,
                                   (LDS_AS unsigned int*)l, 16, 0, 0);
}

// bijective XCD swizzle (m204): contiguous chunk of wg-ids per XCD
__device__ __forceinline__ int xcd_swz(int orig, int nwg) {
  int q = nwg >> 3, r = nwg & 7;
  int xcd = orig & 7, rest = orig >> 3;
  return (xcd < r ? xcd * (q + 1) : r * (q + 1) + (xcd - r) * q) + rest;
}

#define VMW4 asm volatile("s_waitcnt vmcnt(4)" ::: "memory")
#define VMW3 asm volatile("s_waitcnt vmcnt(3)" ::: "memory")
#define VMW0 asm volatile("s_waitcnt vmcnt(0)" ::: "memory")

// ---------------------------------------------------------------- cast x ---
__global__ void castx(const float* __restrict__ in, unsigned short* __restrict__ out, int n) {
  int i = (blockIdx.x * 256 + threadIdx.x) * 4;
  if (i < n) {
    float4 f = *(const float4*)&in[i];
    u16x4 o;
    o[0] = f2bf(f.x); o[1] = f2bf(f.y); o[2] = f2bf(f.z); o[3] = f2bf(f.w);
    *(u16x4*)&out[i] = o;
  }
}

// ------------------------------------- Wq/Wk/Wv transpose+cast (1 launch) --
__global__ void tcast3(const float* __restrict__ Wq, const float* __restrict__ Wk,
                       const float* __restrict__ Wv, unsigned short* __restrict__ out,
                       float qscale) {
  __shared__ float tile[32][33];
  const int R = 768, C = 64;
  int z = blockIdx.z, wsel = z / 12, head = z % 12;
  const float* in = (wsel == 0 ? Wq : wsel == 1 ? Wk : Wv) + (size_t)head * R * C;
  unsigned short* outb = out + (size_t)wsel * R * R + (size_t)head * R * C;
  float scale = wsel == 0 ? qscale : 1.0f;
  int bx = blockIdx.x * 32;  // C dim
  int by = blockIdx.y * 32;  // R dim
  int tx = threadIdx.x, ty = threadIdx.y;
  #pragma unroll
  for (int i = 0; i < 32; i += 8)
    tile[ty + i][tx] = in[(size_t)(by + ty + i) * C + bx + tx];
  __syncthreads();
  #pragma unroll
  for (int i = 0; i < 32; i += 8)
    outb[(size_t)(bx + ty + i) * R + by + tx] = f2bf(tile[tx][ty + i] * scale);
}

// -------------------------------- Wo/W1/W2 transpose+cast in one launch ----
__global__ void tcastW(const float* __restrict__ Wo, const float* __restrict__ W1,
                       const float* __restrict__ W2, unsigned short* __restrict__ woT,
                       unsigned short* __restrict__ w1T, unsigned short* __restrict__ w2T) {
  __shared__ float tile[32][33];
  int id = blockIdx.x;
  const float* in; unsigned short* out; int C, gx, R;
  if (id < 576)       {           in = Wo; out = woT; C = 768;  gx = 24; R = 768; }
  else if (id < 2880) { id -= 576;  in = W1; out = w1T; C = 3072; gx = 96; R = 768; }
  else                { id -= 2880; in = W2; out = w2T; C = 768;  gx = 24; R = 3072; }
  int bx = (id % gx) * 32;   // C dim
  int by = (id / gx) * 32;   // R dim
  int tx = threadIdx.x, ty = threadIdx.y;
  #pragma unroll
  for (int i = 0; i < 32; i += 8)
    tile[ty + i][tx] = in[(size_t)(by + ty + i) * C + bx + tx];
  __syncthreads();
  #pragma unroll
  for (int i = 0; i < 32; i += 8)
    out[(size_t)(bx + ty + i) * R + by + tx] = f2bf(tile[tx][ty + i]);
}

// --------------------------------------------------------- GEMM 128x128 ---
// C[M,N] = A[M,K] @ Bt[N,K]^T ; EPI bits: 1 bias, 2 relu, 4 resid(fp32),
// 8 fp32 store, 16 bf16 store, 32 QKV split bf16 store, 64 (with 32):
// V segment stored transposed to Vt [B,H,hs,S].
// EPI == 1|2|16 (W1): LDS-coalesced epilogue (C-tile bounced via Alds/Blds,
// 16B stores) to cut per-block fixed cost.
// K-loop: R9 counted-vmcnt double-buffer.
template <int EPI, int MAP>
__global__ void gemm_bf16(const unsigned short* __restrict__ A,
                          const unsigned short* __restrict__ Bt,
                          const float* __restrict__ bias,
                          const float* __restrict__ resid,
                          float* __restrict__ Cf,
                          unsigned short* __restrict__ Cb,
                          unsigned short* __restrict__ Vt,
                          int M, int N, int K, int gy, size_t segN) {
  __shared__ unsigned short Alds[2][128 * 32];
  __shared__ unsigned short Blds[2][128 * 32];
  const int tid = threadIdx.x;
  const int lane = tid & 63;
  const int w = tid >> 6;
  const int wm = w & 1, wn = w >> 1;

  int bm, bn;
  if constexpr (MAP == 2) {                    // QKV: gy == 18, grid 1152
    const int xcd = blockIdx.x & 7, rest = blockIdx.x >> 3;  // [0,144)
    if (rest < 128) { bm = (rest >> 1) * 128; bn = (xcd * 2 + (rest & 1)) * 128; }
    else { int r2 = rest - 128; bm = (xcd * 8 + (r2 & 7)) * 128; bn = (16 + (r2 >> 3)) * 128; }
  } else {
    const int wg = xcd_swz(blockIdx.x, gridDim.x);
    const int gsz = 8 * gy;
    const int group = wg / gsz;
    const int rem = wg - group * gsz;
    bm = (group * 8 + (rem & 7)) * 128;
    bn = (rem >> 3) * 128;
  }

  f32x4 acc[4][4] = {};

  const int r0 = tid >> 2;
  const int c0 = (tid & 3) * 8;

  // prologue: stage tile 0 into buf 0; full drain once
  #pragma unroll
  for (int i = 0; i < 2; ++i) {
    int row = r0 + i * 64;
    gload16(&A[(size_t)(bm + row) * K + c0], &Alds[0][row * 32 + c0]);
    gload16(&Bt[(size_t)(bn + row) * K + c0], &Blds[0][row * 32 + c0]);
  }
  __syncthreads();

  int buf = 0;
  for (int k0 = 0; k0 < K; k0 += 32) {
    if (k0 + 32 < K) {
      #pragma unroll
      for (int i = 0; i < 2; ++i) {
        int row = r0 + i * 64;
        gload16(&A[(size_t)(bm + row) * K + k0 + 32 + c0], &Alds[buf ^ 1][row * 32 + c0]);
        gload16(&Bt[(size_t)(bn + row) * K + k0 + 32 + c0], &Blds[buf ^ 1][row * 32 + c0]);
      }
      VMW4;      // waits only the 4 loads of tile t (one K-step old)
    } else {
      VMW0;      // tail: current tile's stage must be complete
    }
    __builtin_amdgcn_s_barrier();    // all waves confirmed stage(t) landed

    bf16x8 af[4], bf[4];
    #pragma unroll
    for (int m = 0; m < 4; ++m)
      af[m] = *(const bf16x8*)&Alds[buf][(wm * 64 + m * 16 + (lane & 15)) * 32 + (lane >> 4) * 8];
    #pragma unroll
    for (int n = 0; n < 4; ++n)
      bf[n] = *(const bf16x8*)&Blds[buf][(wn * 64 + n * 16 + (lane & 15)) * 32 + (lane >> 4) * 8];
    #pragma unroll
    for (int m = 0; m < 4; ++m)
      #pragma unroll
      for (int n = 0; n < 4; ++n)
        acc[m][n] = __builtin_amdgcn_mfma_f32_16x16x32_bf16(af[m], bf[n], acc[m][n], 0, 0, 0);

    __builtin_amdgcn_s_barrier();    // reads(t) consumed before stage(t+2) overwrites
    buf ^= 1;
  }

  const int crow0 = bm + wm * 64 + ((lane >> 4)) * 4;
  const int ccol0 = bn + wn * 64 + (lane & 15);

  if constexpr (EPI == (1 | 2 | 16)) {
    // ---- coalesced epilogue (W1): bounce C-tile through LDS, 16B stores
    unsigned short* C0 = &Alds[0][0];   // rows 0-63   (8192 shorts)
    unsigned short* C1 = &Blds[0][0];   // rows 64-127
    #pragma unroll
    for (int m = 0; m < 4; ++m) {
      #pragma unroll
      for (int n = 0; n < 4; ++n) {
        int col = wn * 64 + n * 16 + (lane & 15);
        #pragma unroll
        for (int r = 0; r < 4; ++r) {
          int rl = m * 16 + (lane >> 4) * 4 + r;   // local row within half
          float v = acc[m][n][r] + bias[bn + col];
          v = fmaxf(v, 0.f);
          (wm ? C1 : C0)[rl * 128 + col] = f2bf(v);
        }
      }
    }
    __syncthreads();
    const int rr = tid >> 4;           // 0..15
    const int ch = (tid & 15) * 8;     // col chunk (shorts)
    #pragma unroll
    for (int p = 0; p < 8; ++p) {
      int row = p * 16 + rr;
      bf16x8 vv = *(const bf16x8*)&(row < 64 ? C0 : C1)[(row & 63) * 128 + ch];
      *(bf16x8*)&Cb[(size_t)(bm + row) * N + bn + ch] = vv;
    }
  } else {
    const int seg = bn / 768;                     // block-constant (768%128==0)
    const int lcol0 = (bn % 768) + wn * 64 + (lane & 15);
    #pragma unroll
    for (int m = 0; m < 4; ++m) {
      #pragma unroll
      for (int n = 0; n < 4; ++n) {
        int col = ccol0 + n * 16;
        #pragma unroll
        for (int r = 0; r < 4; ++r) {
          int row = crow0 + m * 16 + r;
          float v = acc[m][n][r];
          if constexpr (EPI & 1) v += bias[col];
          if constexpr (EPI & 4) v += resid[(size_t)row * N + col];
          if constexpr (EPI & 2) v = fmaxf(v, 0.f);
          if constexpr (EPI & 8) Cf[(size_t)row * N + col] = v;
          if constexpr (EPI & 16) Cb[(size_t)row * N + col] = f2bf(v);
          if constexpr (EPI & 32) {
            int lc = lcol0 + n * 16;
            if ((EPI & 64) && seg == 2) {
              int hh = lc >> 6, e = lc & 63;
              int bb = row >> 11, s = row & 2047;
              Vt[((size_t)(bb * 12 + hh) * 64 + e) * 2048 + s] = f2bf(v);
            } else {
              Cb[(size_t)seg * segN + (size_t)row * 768 + lc] = f2bf(v);
            }
          }
        }
      }
    }
  }
}

// ---------------------------------------------------------- GEMM 128x64 ---
// For Wo / W2 (N=768): 768 blocks = exactly 3/CU, no quantization tail.
// 4 waves in 2(m)x2(n); each wave 64x32 = 4x2 frags, 8 MFMA/step.
// Staging 3 gload16/thread/step -> vmcnt(3) ledger.
template <int EPI>
__global__ void gemm_n64(const unsigned short* __restrict__ A,
                         const unsigned short* __restrict__ Bt,
                         const float* __restrict__ bias,
                         const float* __restrict__ resid,
                         float* __restrict__ Cf,
                         unsigned short* __restrict__ Cb,
                         int M, int N, int K, int gy) {
  __shared__ unsigned short Alds[2][128 * 32];
  __shared__ unsigned short Blds[2][64 * 32];
  const int tid = threadIdx.x;
  const int lane = tid & 63;
  const int w = tid >> 6;
  const int wm = w >> 1, wn = w & 1;

  const int wg = xcd_swz(blockIdx.x, gridDim.x);
  const int gsz = 8 * gy;
  const int group = wg / gsz;
  const int rem = wg - group * gsz;
  const int bm = (group * 8 + (rem & 7)) * 128;
  const int bn = (rem >> 3) * 64;

  f32x4 acc[4][2] = {};

  const int r0 = tid >> 2;          // 0..63
  const int c0 = (tid & 3) * 8;

  // prologue
  #pragma unroll
  for (int i = 0; i < 2; ++i)
    gload16(&A[(size_t)(bm + r0 + i * 64) * K + c0], &Alds[0][(r0 + i * 64) * 32 + c0]);
  gload16(&Bt[(size_t)(bn + r0) * K + c0], &Blds[0][r0 * 32 + c0]);
  __syncthreads();

  int buf = 0;
  for (int k0 = 0; k0 < K; k0 += 32) {
    if (k0 + 32 < K) {
      #pragma unroll
      for (int i = 0; i < 2; ++i)
        gload16(&A[(size_t)(bm + r0 + i * 64) * K + k0 + 32 + c0],
                &Alds[buf ^ 1][(r0 + i * 64) * 32 + c0]);
      gload16(&Bt[(size_t)(bn + r0) * K + k0 + 32 + c0], &Blds[buf ^ 1][r0 * 32 + c0]);
      VMW3;
    } else {
      VMW0;
    }
    __builtin_amdgcn_s_barrier();

    bf16x8 af[4], bf[2];
    #pragma unroll
    for (int m = 0; m < 4; ++m)
      af[m] = *(const bf16x8*)&Alds[buf][(wm * 64 + m * 16 + (lane & 15)) * 32 + (lane >> 4) * 8];
    #pragma unroll
    for (int n = 0; n < 2; ++n)
      bf[n] = *(const bf16x8*)&Blds[buf][(wn * 32 + n * 16 + (lane & 15)) * 32 + (lane >> 4) * 8];
    #pragma unroll
    for (int m = 0; m < 4; ++m)
      #pragma unroll
      for (int n = 0; n < 2; ++n)
        acc[m][n] = __builtin_amdgcn_mfma_f32_16x16x32_bf16(af[m], bf[n], acc[m][n], 0, 0, 0);

    __builtin_amdgcn_s_barrier();
    buf ^= 1;
  }

  const int crow0 = bm + wm * 64 + (lane >> 4) * 4;
  const int ccol0 = bn + wn * 32 + (lane & 15);
  #pragma unroll
  for (int m = 0; m < 4; ++m) {
    #pragma unroll
    for (int n = 0; n < 2; ++n) {
      int col = ccol0 + n * 16;
      #pragma unroll
      for (int r = 0; r < 4; ++r) {
        int row = crow0 + m * 16 + r;
        float v = acc[m][n][r];
        if constexpr (EPI & 1) v += bias[col];
        if constexpr (EPI & 4) v += resid[(size_t)row * N + col];
        if constexpr (EPI & 2) v = fmaxf(v, 0.f);
        if constexpr (EPI & 8) Cf[(size_t)row * N + col] = v;
        if constexpr (EPI & 16) Cb[(size_t)row * N + col] = f2bf(v);
      }
    }
  }
}

// ------------------------------------------------------------- attention ---
// Swapped-QK^T causal flash attention, paired q-blocks, static-max softmax,
// counted-vmcnt barriers (unchanged from R9/R12).
__global__ void attn_fwd(const unsigned short* __restrict__ q,
                         const unsigned short* __restrict__ k,
                         const unsigned short* __restrict__ vT,
                         unsigned short* __restrict__ z) {
  __shared__ unsigned short Klds[2 * 2 * 64 * 32];
  __shared__ unsigned short Vlds[2 * 2 * 64 * 32];
  __shared__ unsigned short Plds[4 * 16 * 72];

  const int wgid = xcd_swz(blockIdx.x, gridDim.x);
  const int pi = wgid & 15;
  const int bh = wgid >> 4;
  const int b = bh / 12, h = bh % 12;
  const int tid = threadIdx.x, lane = tid & 63, w = tid >> 6;
  const int q16 = lane & 15;
  const int qt  = lane >> 4;
  const int rdc = ((qt ^ ((q16 >> 1) & 3)) * 8);

  const int srow = tid >> 2;
  const int sdc  = (tid & 3) * 8;
  const int sgc  = (((tid & 3) ^ ((srow >> 1) & 3)) * 8);
  const size_t kbase = (size_t)(b * 2048) * 768 + h * 64;
  const size_t vbase = (size_t)((b * 12 + h) * 64) * 2048;
  unsigned short* Pw = &Plds[w * 16 * 72];

  #pragma unroll 1
  for (int seg = 0; seg < 2; ++seg) {
    const int qb = seg == 0 ? pi : 31 - pi;
    const int q0 = qb * 64;
    const int nt = qb + 1;

    const int qrow = q0 + w * 16 + q16;
    const size_t qoff = (size_t)(b * 2048 + qrow) * 768 + h * 64 + qt * 8;
    bf16x8 qf0 = *(const bf16x8*)&q[qoff];
    bf16x8 qf1 = *(const bf16x8*)&q[qoff + 32];

    f32x4 accO[4] = {};
    float lrow = 0.f;

    #pragma unroll
    for (int i = 0; i < 2; ++i) {
      gload16(&k[kbase + (size_t)srow * 768 + i * 32 + sgc],
              &Klds[i * 2048 + srow * 32 + sdc]);
      gload16(&vT[vbase + (size_t)srow * 2048 + i * 32 + sgc],
              &Vlds[i * 2048 + srow * 32 + sdc]);
    }
    __syncthreads();     // full drain once per segment

    int buf = 0;
    for (int t = 0; t < nt; ++t) {
      if (t + 1 < nt) {
        const int kv1 = (t + 1) * 64;
        const int bo = (buf ^ 1) * 4096;
        #pragma unroll
        for (int i = 0; i < 2; ++i) {
          gload16(&k[kbase + (size_t)(kv1 + srow) * 768 + i * 32 + sgc],
                  &Klds[bo + i * 2048 + srow * 32 + sdc]);
          gload16(&vT[vbase + (size_t)srow * 2048 + kv1 + i * 32 + sgc],
                  &Vlds[bo + i * 2048 + srow * 32 + sdc]);
        }
        VMW4;            // waits only stage(t) (issued last iteration)
      } else {
        VMW0;
      }
      __builtin_amdgcn_s_barrier();   // stage(t) visible to all waves

      const int kv0 = t * 64;
      const int kb_ = buf * 4096;

      // S = K Q^T: 4 independent k0-MFMAs, then 4 k1-MFMAs
      bf16x8 kf0[4], kf1[4];
      #pragma unroll
      for (int n = 0; n < 4; ++n) {
        kf0[n] = *(const bf16x8*)&Klds[kb_ + 0 * 2048 + (n * 16 + q16) * 32 + rdc];
        kf1[n] = *(const bf16x8*)&Klds[kb_ + 1 * 2048 + (n * 16 + q16) * 32 + rdc];
      }
      f32x4 s[4];
      __builtin_amdgcn_s_setprio(1);
      #pragma unroll
      for (int n = 0; n < 4; ++n) {
        f32x4 zz = {};
        s[n] = __builtin_amdgcn_mfma_f32_16x16x32_bf16(kf0[n], qf0, zz, 0, 0, 0);
      }
      #pragma unroll
      for (int n = 0; n < 4; ++n)
        s[n] = __builtin_amdgcn_mfma_f32_16x16x32_bf16(kf1[n], qf1, s[n], 0, 0, 0);
      __builtin_amdgcn_s_setprio(0);

      if (t == nt - 1) {
        const int rowg = q0 + w * 16 + q16;
        #pragma unroll
        for (int n = 0; n < 4; ++n)
          #pragma unroll
          for (int r = 0; r < 4; ++r)
            if (kv0 + n * 16 + qt * 4 + r > rowg) s[n][r] = -3.0e38f;
      }

      // p = exp2(s); in-lane partial row-sum (cross-lane sum deferred)
      #pragma unroll
      for (int n = 0; n < 4; ++n)
        #pragma unroll
        for (int r = 0; r < 4; ++r) { s[n][r] = exp2f(s[n][r]); lrow += s[n][r]; }

      #pragma unroll
      for (int n = 0; n < 4; ++n) {
        unsigned int lo, hi;
        asm("v_cvt_pk_bf16_f32 %0, %1, %2" : "=v"(lo) : "v"(s[n][0]), "v"(s[n][1]));
        asm("v_cvt_pk_bf16_f32 %0, %1, %2" : "=v"(hi) : "v"(s[n][2]), "v"(s[n][3]));
        uint2 pk; pk.x = lo; pk.y = hi;
        *(uint2*)&Pw[q16 * 72 + n * 16 + qt * 4] = pk;
      }

      __builtin_amdgcn_s_setprio(1);
      #pragma unroll
      for (int kk = 0; kk < 2; ++kk) {
        bf16x8 pf = *(const bf16x8*)&Pw[q16 * 72 + kk * 32 + qt * 8];
        #pragma unroll
        for (int n = 0; n < 4; ++n) {
          bf16x8 vf = *(const bf16x8*)&Vlds[kb_ + kk * 2048 + (n * 16 + q16) * 32 + rdc];
          accO[n] = __builtin_amdgcn_mfma_f32_16x16x32_bf16(pf, vf, accO[n], 0, 0, 0);
        }
      }
      __builtin_amdgcn_s_setprio(0);

      __builtin_amdgcn_s_barrier();   // reads(t) consumed before stage(t+2) overwrites
      buf ^= 1;
    }

    // epilogue: complete the row sum across kv-quarter lanes, then divide
    lrow += __shfl_xor(lrow, 16);
    lrow += __shfl_xor(lrow, 32);
    #pragma unroll
    for (int r = 0; r < 4; ++r) {
      float lr = __int_as_float(__builtin_amdgcn_ds_bpermute((qt * 4 + r) * 4,
                                                             __float_as_int(lrow)));
      float linv = 1.0f / lr;
      int rowg = q0 + w * 16 + qt * 4 + r;
      #pragma unroll
      for (int n = 0; n < 4; ++n)
        z[(size_t)(b * 2048 + rowg) * 768 + h * 64 + n * 16 + q16]
            = f2bf(accO[n][r] * linv);
    }
  }
}

// ---------------------------------------------------------------- launch ---
extern "C" void kernel_launch(void* const* d_in, const int* in_sizes, int n_in,
                              void* d_out, int out_size, void* d_ws, size_t ws_size,
                              hipStream_t stream) {
  const float* x  = (const float*)d_in[0];
  const float* Wq = (const float*)d_in[1];
  const float* Wk = (const float*)d_in[2];
  const float* Wv = (const float*)d_in[3];
  const float* Wo = (const float*)d_in[4];
  const float* bo = (const float*)d_in[5];
  const float* W1 = (const float*)d_in[6];
  const float* b1 = (const float*)d_in[7];
  const float* W2 = (const float*)d_in[8];
  const float* b2 = (const float*)d_in[9];
  float* out = (float*)d_out;

  const int B = 4, S = 2048, D = 768, H = 12, hs = 64, F = 3072;
  const int M = B * S;                 // 8192
  const size_t MD = (size_t)M * D;     // 6291456

  unsigned short* xb   = (unsigned short*)d_ws;
  unsigned short* qb   = xb + MD;
  unsigned short* kb   = qb + MD;
  unsigned short* vb   = kb + MD;      // unused (V goes straight to vT)
  unsigned short* hbuf = xb;           // [M, F] bf16, reuse
  unsigned short* vT   = vb + MD;
  unsigned short* zb   = vT + MD;
  float*          z2f  = (float*)(zb + MD);
  unsigned short* z2b  = (unsigned short*)(z2f + MD);
  unsigned short* wqkvT= z2b + MD;     // [2304][768] bf16
  unsigned short* woT  = wqkvT + 3 * (size_t)D * D;
  unsigned short* w1T  = woT + (size_t)D * D;
  unsigned short* w2T  = w1T + (size_t)D * F;

  dim3 tb(32, 8);

  castx<<<dim3((int)(MD / 4 / 256)), 256, 0, stream>>>(x, xb, (int)MD);

  // q scale folds 1/sqrt(64) AND log2(e): softmax runs in exp2 domain
  const float QS = 0.125f * 1.4426950408889634f;
  tcast3<<<dim3(hs / 32, D / 32, 3 * H), tb, 0, stream>>>(Wq, Wk, Wv, wqkvT, QS);
  tcastW<<<dim3(5184), tb, 0, stream>>>(Wo, W1, W2, woT, w1T, w2T);

  // fused QKV: [M,768] @ [768,2304]; q->qb, k->kb, v-> vT (transposed store)
  {
    int gy = 3 * D / 128;  // 18
    gemm_bf16<32 | 64, 2><<<dim3(64 * gy), 256, 0, stream>>>(
        xb, wqkvT, nullptr, nullptr, nullptr, qb, vT, M, 3 * D, D, gy, MD);
  }

  attn_fwd<<<dim3((S / 128) * B * H), 256, 0, stream>>>(qb, kb, vT, zb);

  // z @ Wo + bo + x -> z2 (fp32 + bf16), 128x64 tiles: 768 blocks = 3/CU
  {
    int gy = D / 64;  // 12
    gemm_n64<1 | 4 | 8 | 16><<<dim3(64 * gy), 256, 0, stream>>>(
        zb, woT, bo, x, z2f, z2b, M, D, D, gy);
  }
  // relu(z2 @ W1 + b1) -> h (bf16), 128² + coalesced epilogue
  {
    int gy = F / 128;  // 24
    gemm_bf16<1 | 2 | 16, 0><<<dim3(64 * gy), 256, 0, stream>>>(
        z2b, w1T, b1, nullptr, nullptr, hbuf, nullptr, M, F, D, gy, 0);
  }
  // h @ W2 + b2 + z2 -> out (fp32), 128x64 tiles: 768 blocks = 3/CU
  {
    int gy = D / 64;  // 12
    gemm_n64<1 | 4 | 8><<<dim3(64 * gy), 256, 0, stream>>>(
        hbuf, w2T, b2, z2f, out, nullptr, M, D, F, gy);
  }
}

// Round 14
// 268.460 us; speedup vs baseline: 1.0716x; 1.0716x over previous
//
#include <hip/hip_runtime.h>

// ---------------------------------------------------------------------------
// TransformerBlock on MI355X (gfx950): bf16 MFMA pipeline
//   B=4 S=2048 D=768 H=12 hs=64 F=3072, M=B*S=8192
// Round 14: revert to R9-best config (273 us): QKV split store + vtrans,
//           scalar epilogues, counted-vmcnt double-buffer 128x128 GEMM,
//           static-max swapped-QK^T attention. Kept: tcastW merge.
//           NEW: W1 on 256x128 tile (gemm_w1, 768 blocks = 3/CU exact,
//           halves per-block fixed cost + B re-fetch).
// ---------------------------------------------------------------------------

typedef __attribute__((ext_vector_type(4))) float f32x4;
typedef __attribute__((ext_vector_type(8))) short bf16x8;   // 8 bf16 in 4 VGPRs
typedef __attribute__((ext_vector_type(4))) unsigned short u16x4;

#define GLB_AS __attribute__((address_space(1)))
#define LDS_AS __attribute__((address_space(3)))

__device__ __forceinline__ unsigned short f2bf(float f) {
  unsigned int u = __float_as_uint(f);
  u = (u + 0x7FFFu + ((u >> 16) & 1u)) >> 16;   // RNE
  return (unsigned short)u;
}

__device__ __forceinline__ void gload16(const void* g, void* l) {
  __builtin_amdgcn_global_load_lds((const GLB_AS unsigned int*)g,
                                   (LDS_AS unsigned int*)l, 16, 0, 0);
}

// bijective XCD swizzle (m204): contiguous chunk of wg-ids per XCD
__device__ __forceinline__ int xcd_swz(int orig, int nwg) {
  int q = nwg >> 3, r = nwg & 7;
  int xcd = orig & 7, rest = orig >> 3;
  return (xcd < r ? xcd * (q + 1) : r * (q + 1) + (xcd - r) * q) + rest;
}

#define VMW4 asm volatile("s_waitcnt vmcnt(4)" ::: "memory")
#define VMW3 asm volatile("s_waitcnt vmcnt(3)" ::: "memory")
#define VMW0 asm volatile("s_waitcnt vmcnt(0)" ::: "memory")

// ---------------------------------------------------------------- cast x ---
__global__ void castx(const float* __restrict__ in, unsigned short* __restrict__ out, int n) {
  int i = (blockIdx.x * 256 + threadIdx.x) * 4;
  if (i < n) {
    float4 f = *(const float4*)&in[i];
    u16x4 o;
    o[0] = f2bf(f.x); o[1] = f2bf(f.y); o[2] = f2bf(f.z); o[3] = f2bf(f.w);
    *(u16x4*)&out[i] = o;
  }
}

// ------------------------------------- Wq/Wk/Wv transpose+cast (1 launch) --
__global__ void tcast3(const float* __restrict__ Wq, const float* __restrict__ Wk,
                       const float* __restrict__ Wv, unsigned short* __restrict__ out,
                       float qscale) {
  __shared__ float tile[32][33];
  const int R = 768, C = 64;
  int z = blockIdx.z, wsel = z / 12, head = z % 12;
  const float* in = (wsel == 0 ? Wq : wsel == 1 ? Wk : Wv) + (size_t)head * R * C;
  unsigned short* outb = out + (size_t)wsel * R * R + (size_t)head * R * C;
  float scale = wsel == 0 ? qscale : 1.0f;
  int bx = blockIdx.x * 32;  // C dim
  int by = blockIdx.y * 32;  // R dim
  int tx = threadIdx.x, ty = threadIdx.y;
  #pragma unroll
  for (int i = 0; i < 32; i += 8)
    tile[ty + i][tx] = in[(size_t)(by + ty + i) * C + bx + tx];
  __syncthreads();
  #pragma unroll
  for (int i = 0; i < 32; i += 8)
    outb[(size_t)(bx + ty + i) * R + by + tx] = f2bf(tile[tx][ty + i] * scale);
}

// -------------------------------- Wo/W1/W2 transpose+cast in one launch ----
__global__ void tcastW(const float* __restrict__ Wo, const float* __restrict__ W1,
                       const float* __restrict__ W2, unsigned short* __restrict__ woT,
                       unsigned short* __restrict__ w1T, unsigned short* __restrict__ w2T) {
  __shared__ float tile[32][33];
  int id = blockIdx.x;
  const float* in; unsigned short* out; int C, gx, R;
  if (id < 576)       {           in = Wo; out = woT; C = 768;  gx = 24; R = 768; }
  else if (id < 2880) { id -= 576;  in = W1; out = w1T; C = 3072; gx = 96; R = 768; }
  else                { id -= 2880; in = W2; out = w2T; C = 768;  gx = 24; R = 3072; }
  int bx = (id % gx) * 32;   // C dim
  int by = (id / gx) * 32;   // R dim
  int tx = threadIdx.x, ty = threadIdx.y;
  #pragma unroll
  for (int i = 0; i < 32; i += 8)
    tile[ty + i][tx] = in[(size_t)(by + ty + i) * C + bx + tx];
  __syncthreads();
  #pragma unroll
  for (int i = 0; i < 32; i += 8)
    out[(size_t)(bx + ty + i) * R + by + tx] = f2bf(tile[tx][ty + i]);
}

// ------------------------------------------------- v -> vT (bf16->bf16) ----
__global__ void vtrans(const unsigned short* __restrict__ v, unsigned short* __restrict__ vT) {
  __shared__ unsigned short tile[32][33];
  int bh = blockIdx.z, b = bh / 12, h = bh % 12;
  int s0 = blockIdx.x * 32, e0 = blockIdx.y * 32;
  int tx = threadIdx.x, ty = threadIdx.y;
  #pragma unroll
  for (int i = 0; i < 32; i += 8)
    tile[ty + i][tx] = v[(size_t)(b * 2048 + s0 + ty + i) * 768 + h * 64 + e0 + tx];
  __syncthreads();
  #pragma unroll
  for (int i = 0; i < 32; i += 8)
    vT[(size_t)((b * 12 + h) * 64 + e0 + ty + i) * 2048 + s0 + tx] = tile[tx][ty + i];
}

// --------------------------------------------------------- GEMM 128x128 ---
// C[M,N] = A[M,K] @ Bt[N,K]^T ; EPI bits: 1 bias, 2 relu, 4 resid(fp32),
// 8 fp32 store, 16 bf16 store, 32 QKV split bf16 store.
// K-loop: counted-vmcnt double-buffer (R9 proven).
template <int EPI>
__global__ void gemm_bf16(const unsigned short* __restrict__ A,
                          const unsigned short* __restrict__ Bt,
                          const float* __restrict__ bias,
                          const float* __restrict__ resid,
                          float* __restrict__ Cf,
                          unsigned short* __restrict__ Cb,
                          int M, int N, int K, int gy, size_t segN) {
  __shared__ unsigned short Alds[2][128 * 32];
  __shared__ unsigned short Blds[2][128 * 32];
  const int tid = threadIdx.x;
  const int lane = tid & 63;
  const int w = tid >> 6;
  const int wm = w & 1, wn = w >> 1;
  const int wg = xcd_swz(blockIdx.x, gridDim.x);
  const int gsz = 8 * gy;
  const int group = wg / gsz;
  const int rem = wg - group * gsz;
  const int bm = (group * 8 + (rem & 7)) * 128;
  const int bn = (rem >> 3) * 128;

  f32x4 acc[4][4] = {};

  const int r0 = tid >> 2;
  const int c0 = (tid & 3) * 8;

  #pragma unroll
  for (int i = 0; i < 2; ++i) {
    int row = r0 + i * 64;
    gload16(&A[(size_t)(bm + row) * K + c0], &Alds[0][row * 32 + c0]);
    gload16(&Bt[(size_t)(bn + row) * K + c0], &Blds[0][row * 32 + c0]);
  }
  __syncthreads();

  int buf = 0;
  for (int k0 = 0; k0 < K; k0 += 32) {
    if (k0 + 32 < K) {
      #pragma unroll
      for (int i = 0; i < 2; ++i) {
        int row = r0 + i * 64;
        gload16(&A[(size_t)(bm + row) * K + k0 + 32 + c0], &Alds[buf ^ 1][row * 32 + c0]);
        gload16(&Bt[(size_t)(bn + row) * K + k0 + 32 + c0], &Blds[buf ^ 1][row * 32 + c0]);
      }
      VMW4;      // waits only the 4 loads of tile t (one K-step old)
    } else {
      VMW0;
    }
    __builtin_amdgcn_s_barrier();

    bf16x8 af[4], bf[4];
    #pragma unroll
    for (int m = 0; m < 4; ++m)
      af[m] = *(const bf16x8*)&Alds[buf][(wm * 64 + m * 16 + (lane & 15)) * 32 + (lane >> 4) * 8];
    #pragma unroll
    for (int n = 0; n < 4; ++n)
      bf[n] = *(const bf16x8*)&Blds[buf][(wn * 64 + n * 16 + (lane & 15)) * 32 + (lane >> 4) * 8];
    #pragma unroll
    for (int m = 0; m < 4; ++m)
      #pragma unroll
      for (int n = 0; n < 4; ++n)
        acc[m][n] = __builtin_amdgcn_mfma_f32_16x16x32_bf16(af[m], bf[n], acc[m][n], 0, 0, 0);

    __builtin_amdgcn_s_barrier();
    buf ^= 1;
  }

  const int crow0 = bm + wm * 64 + ((lane >> 4)) * 4;
  const int ccol0 = bn + wn * 64 + (lane & 15);
  const int seg = bn / 768;                       // block-constant (768%128==0)
  const int lcol0 = (bn % 768) + wn * 64 + (lane & 15);
  #pragma unroll
  for (int m = 0; m < 4; ++m) {
    #pragma unroll
    for (int n = 0; n < 4; ++n) {
      int col = ccol0 + n * 16;
      #pragma unroll
      for (int r = 0; r < 4; ++r) {
        int row = crow0 + m * 16 + r;
        float v = acc[m][n][r];
        if constexpr (EPI & 1) v += bias[col];
        if constexpr (EPI & 4) v += resid[(size_t)row * N + col];
        if constexpr (EPI & 2) v = fmaxf(v, 0.f);
        if constexpr (EPI & 8) Cf[(size_t)row * N + col] = v;
        if constexpr (EPI & 16) Cb[(size_t)row * N + col] = f2bf(v);
        if constexpr (EPI & 32)
          Cb[(size_t)seg * segN + (size_t)row * 768 + lcol0 + n * 16] = f2bf(v);
      }
    }
  }
}

// --------------------------------------------------------- GEMM 256x128 ---
// For W1 (M=8192, N=3072): 32x24 = 768 blocks = exactly 3/CU.
// 8 waves (4m x 2n), each 64x64 -> acc[4][4]; BK=32; 48 KB LDS dbuf.
// Staging 3 gload16/thread/step -> vmcnt(3) ledger.
#define W1STG(bb, kt) {                                                    \
    _Pragma("unroll") for (int i = 0; i < 2; ++i) {                        \
      int ch = tid + 512 * i;                                              \
      gload16(&A[(size_t)(bm + (ch >> 2)) * K + (kt) + (ch & 3) * 8],      \
              &Alds[bb][(ch >> 2) * 32 + (ch & 3) * 8]);                   \
    }                                                                      \
    gload16(&Bt[(size_t)(bn + (tid >> 2)) * K + (kt) + (tid & 3) * 8],     \
            &Blds[bb][(tid >> 2) * 32 + (tid & 3) * 8]); }

template <int EPI>
__global__ __launch_bounds__(512, 2)
void gemm_w1(const unsigned short* __restrict__ A,
             const unsigned short* __restrict__ Bt,
             const float* __restrict__ bias,
             unsigned short* __restrict__ Cb,
             int M, int N, int K, int gy) {
  __shared__ unsigned short Alds[2][256 * 32];
  __shared__ unsigned short Blds[2][128 * 32];
  const int tid = threadIdx.x;
  const int lane = tid & 63;
  const int w = tid >> 6;
  const int wr = w >> 1, wc = w & 1;            // 4 x 2 wave grid (64x64 each)
  const int q16 = lane & 15, qt = lane >> 4;

  const int wg = xcd_swz(blockIdx.x, gridDim.x);
  const int gsz = 8 * gy;                       // gy = N/128 = 24
  const int group = wg / gsz;                   // 0..3 (32 bm-tiles / 8)
  const int rem = wg - group * gsz;
  const int bm = (group * 8 + (rem & 7)) * 256;
  const int bn = (rem >> 3) * 128;

  f32x4 acc[4][4] = {};

  W1STG(0, 0);
  __syncthreads();

  int buf = 0;
  for (int k0 = 0; k0 < K; k0 += 32) {
    if (k0 + 32 < K) {
      W1STG(buf ^ 1, k0 + 32);
      VMW3;      // waits only the 3 loads of tile t (one K-step old)
    } else {
      VMW0;
    }
    __builtin_amdgcn_s_barrier();

    bf16x8 af[4], bf[4];
    #pragma unroll
    for (int m = 0; m < 4; ++m)
      af[m] = *(const bf16x8*)&Alds[buf][(wr * 64 + m * 16 + q16) * 32 + qt * 8];
    #pragma unroll
    for (int n = 0; n < 4; ++n)
      bf[n] = *(const bf16x8*)&Blds[buf][(wc * 64 + n * 16 + q16) * 32 + qt * 8];
    #pragma unroll
    for (int m = 0; m < 4; ++m)
      #pragma unroll
      for (int n = 0; n < 4; ++n)
        acc[m][n] = __builtin_amdgcn_mfma_f32_16x16x32_bf16(af[m], bf[n], acc[m][n], 0, 0, 0);

    __builtin_amdgcn_s_barrier();
    buf ^= 1;
  }

  const int crow0 = bm + wr * 64 + qt * 4;
  const int ccol0 = bn + wc * 64 + q16;
  #pragma unroll
  for (int m = 0; m < 4; ++m) {
    #pragma unroll
    for (int n = 0; n < 4; ++n) {
      int col = ccol0 + n * 16;
      #pragma unroll
      for (int r = 0; r < 4; ++r) {
        int row = crow0 + m * 16 + r;
        float v = acc[m][n][r];
        if constexpr (EPI & 1) v += bias[col];
        if constexpr (EPI & 2) v = fmaxf(v, 0.f);
        Cb[(size_t)row * N + col] = f2bf(v);
      }
    }
  }
}

// ------------------------------------------------------------- attention ---
// Swapped-QK^T causal flash attention, paired q-blocks, static-max softmax,
// counted-vmcnt barriers (R9 version, unchanged).
__global__ void attn_fwd(const unsigned short* __restrict__ q,
                         const unsigned short* __restrict__ k,
                         const unsigned short* __restrict__ vT,
                         unsigned short* __restrict__ z) {
  __shared__ unsigned short Klds[2 * 2 * 64 * 32];
  __shared__ unsigned short Vlds[2 * 2 * 64 * 32];
  __shared__ unsigned short Plds[4 * 16 * 72];

  const int wgid = xcd_swz(blockIdx.x, gridDim.x);
  const int pi = wgid & 15;
  const int bh = wgid >> 4;
  const int b = bh / 12, h = bh % 12;
  const int tid = threadIdx.x, lane = tid & 63, w = tid >> 6;
  const int q16 = lane & 15;
  const int qt  = lane >> 4;
  const int rdc = ((qt ^ ((q16 >> 1) & 3)) * 8);

  const int srow = tid >> 2;
  const int sdc  = (tid & 3) * 8;
  const int sgc  = (((tid & 3) ^ ((srow >> 1) & 3)) * 8);
  const size_t kbase = (size_t)(b * 2048) * 768 + h * 64;
  const size_t vbase = (size_t)((b * 12 + h) * 64) * 2048;
  unsigned short* Pw = &Plds[w * 16 * 72];

  #pragma unroll 1
  for (int seg = 0; seg < 2; ++seg) {
    const int qb = seg == 0 ? pi : 31 - pi;
    const int q0 = qb * 64;
    const int nt = qb + 1;

    const int qrow = q0 + w * 16 + q16;
    const size_t qoff = (size_t)(b * 2048 + qrow) * 768 + h * 64 + qt * 8;
    bf16x8 qf0 = *(const bf16x8*)&q[qoff];
    bf16x8 qf1 = *(const bf16x8*)&q[qoff + 32];

    f32x4 accO[4] = {};
    float lrow = 0.f;

    #pragma unroll
    for (int i = 0; i < 2; ++i) {
      gload16(&k[kbase + (size_t)srow * 768 + i * 32 + sgc],
              &Klds[i * 2048 + srow * 32 + sdc]);
      gload16(&vT[vbase + (size_t)srow * 2048 + i * 32 + sgc],
              &Vlds[i * 2048 + srow * 32 + sdc]);
    }
    __syncthreads();     // full drain once per segment

    int buf = 0;
    for (int t = 0; t < nt; ++t) {
      if (t + 1 < nt) {
        const int kv1 = (t + 1) * 64;
        const int bo = (buf ^ 1) * 4096;
        #pragma unroll
        for (int i = 0; i < 2; ++i) {
          gload16(&k[kbase + (size_t)(kv1 + srow) * 768 + i * 32 + sgc],
                  &Klds[bo + i * 2048 + srow * 32 + sdc]);
          gload16(&vT[vbase + (size_t)srow * 2048 + kv1 + i * 32 + sgc],
                  &Vlds[bo + i * 2048 + srow * 32 + sdc]);
        }
        VMW4;            // waits only stage(t) (issued last iteration)
      } else {
        VMW0;
      }
      __builtin_amdgcn_s_barrier();   // stage(t) visible to all waves

      const int kv0 = t * 64;
      const int kb_ = buf * 4096;

      // S = K Q^T: 4 independent k0-MFMAs, then 4 k1-MFMAs
      bf16x8 kf0[4], kf1[4];
      #pragma unroll
      for (int n = 0; n < 4; ++n) {
        kf0[n] = *(const bf16x8*)&Klds[kb_ + 0 * 2048 + (n * 16 + q16) * 32 + rdc];
        kf1[n] = *(const bf16x8*)&Klds[kb_ + 1 * 2048 + (n * 16 + q16) * 32 + rdc];
      }
      f32x4 s[4];
      __builtin_amdgcn_s_setprio(1);
      #pragma unroll
      for (int n = 0; n < 4; ++n) {
        f32x4 zz = {};
        s[n] = __builtin_amdgcn_mfma_f32_16x16x32_bf16(kf0[n], qf0, zz, 0, 0, 0);
      }
      #pragma unroll
      for (int n = 0; n < 4; ++n)
        s[n] = __builtin_amdgcn_mfma_f32_16x16x32_bf16(kf1[n], qf1, s[n], 0, 0, 0);
      __builtin_amdgcn_s_setprio(0);

      if (t == nt - 1) {
        const int rowg = q0 + w * 16 + q16;
        #pragma unroll
        for (int n = 0; n < 4; ++n)
          #pragma unroll
          for (int r = 0; r < 4; ++r)
            if (kv0 + n * 16 + qt * 4 + r > rowg) s[n][r] = -3.0e38f;
      }

      // p = exp2(s); in-lane partial row-sum (cross-lane sum deferred)
      #pragma unroll
      for (int n = 0; n < 4; ++n)
        #pragma unroll
        for (int r = 0; r < 4; ++r) { s[n][r] = exp2f(s[n][r]); lrow += s[n][r]; }

      #pragma unroll
      for (int n = 0; n < 4; ++n) {
        unsigned int lo, hi;
        asm("v_cvt_pk_bf16_f32 %0, %1, %2" : "=v"(lo) : "v"(s[n][0]), "v"(s[n][1]));
        asm("v_cvt_pk_bf16_f32 %0, %1, %2" : "=v"(hi) : "v"(s[n][2]), "v"(s[n][3]));
        uint2 pk; pk.x = lo; pk.y = hi;
        *(uint2*)&Pw[q16 * 72 + n * 16 + qt * 4] = pk;
      }

      __builtin_amdgcn_s_setprio(1);
      #pragma unroll
      for (int kk = 0; kk < 2; ++kk) {
        bf16x8 pf = *(const bf16x8*)&Pw[q16 * 72 + kk * 32 + qt * 8];
        #pragma unroll
        for (int n = 0; n < 4; ++n) {
          bf16x8 vf = *(const bf16x8*)&Vlds[kb_ + kk * 2048 + (n * 16 + q16) * 32 + rdc];
          accO[n] = __builtin_amdgcn_mfma_f32_16x16x32_bf16(pf, vf, accO[n], 0, 0, 0);
        }
      }
      __builtin_amdgcn_s_setprio(0);

      __builtin_amdgcn_s_barrier();
      buf ^= 1;
    }

    // epilogue: complete the row sum across kv-quarter lanes, then divide
    lrow += __shfl_xor(lrow, 16);
    lrow += __shfl_xor(lrow, 32);
    #pragma unroll
    for (int r = 0; r < 4; ++r) {
      float lr = __int_as_float(__builtin_amdgcn_ds_bpermute((qt * 4 + r) * 4,
                                                             __float_as_int(lrow)));
      float linv = 1.0f / lr;
      int rowg = q0 + w * 16 + qt * 4 + r;
      #pragma unroll
      for (int n = 0; n < 4; ++n)
        z[(size_t)(b * 2048 + rowg) * 768 + h * 64 + n * 16 + q16]
            = f2bf(accO[n][r] * linv);
    }
  }
}

// ---------------------------------------------------------------- launch ---
extern "C" void kernel_launch(void* const* d_in, const int* in_sizes, int n_in,
                              void* d_out, int out_size, void* d_ws, size_t ws_size,
                              hipStream_t stream) {
  const float* x  = (const float*)d_in[0];
  const float* Wq = (const float*)d_in[1];
  const float* Wk = (const float*)d_in[2];
  const float* Wv = (const float*)d_in[3];
  const float* Wo = (const float*)d_in[4];
  const float* bo = (const float*)d_in[5];
  const float* W1 = (const float*)d_in[6];
  const float* b1 = (const float*)d_in[7];
  const float* W2 = (const float*)d_in[8];
  const float* b2 = (const float*)d_in[9];
  float* out = (float*)d_out;

  const int B = 4, S = 2048, D = 768, H = 12, hs = 64, F = 3072;
  const int M = B * S;                 // 8192
  const size_t MD = (size_t)M * D;     // 6291456

  unsigned short* xb   = (unsigned short*)d_ws;
  unsigned short* qb   = xb + MD;
  unsigned short* kb   = qb + MD;
  unsigned short* vb   = kb + MD;
  unsigned short* hbuf = xb;           // [M, F] bf16, reuse
  unsigned short* vT   = vb + MD;
  unsigned short* zb   = vT + MD;
  float*          z2f  = (float*)(zb + MD);
  unsigned short* z2b  = (unsigned short*)(z2f + MD);
  unsigned short* wqkvT= z2b + MD;     // [2304][768] bf16
  unsigned short* woT  = wqkvT + 3 * (size_t)D * D;
  unsigned short* w1T  = woT + (size_t)D * D;
  unsigned short* w2T  = w1T + (size_t)D * F;

  dim3 tb(32, 8);

  castx<<<dim3((int)(MD / 4 / 256)), 256, 0, stream>>>(x, xb, (int)MD);

  // q scale folds 1/sqrt(64) AND log2(e): softmax runs in exp2 domain
  const float QS = 0.125f * 1.4426950408889634f;
  tcast3<<<dim3(hs / 32, D / 32, 3 * H), tb, 0, stream>>>(Wq, Wk, Wv, wqkvT, QS);
  tcastW<<<dim3(5184), tb, 0, stream>>>(Wo, W1, W2, woT, w1T, w2T);

  // fused QKV: [M,768] @ [768,2304] -> q,k,v bf16 (split store), 1152 blocks
  {
    int gy = 3 * D / 128;  // 18
    gemm_bf16<32><<<dim3(64 * gy), 256, 0, stream>>>(xb, wqkvT, nullptr, nullptr,
                                                     nullptr, qb, M, 3 * D, D, gy, MD);
  }

  vtrans<<<dim3(S / 32, hs / 32, B * H), tb, 0, stream>>>(vb, vT);

  attn_fwd<<<dim3((S / 128) * B * H), 256, 0, stream>>>(qb, kb, vT, zb);

  // z @ Wo + bo + x -> z2 (fp32 + bf16)
  {
    int gy = D / 128;  // 6
    gemm_bf16<1 | 4 | 8 | 16><<<dim3(64 * gy), 256, 0, stream>>>(zb, woT, bo, x,
                                                                 z2f, z2b, M, D, D, gy, 0);
  }
  // relu(z2 @ W1 + b1) -> h (bf16), 256x128 tiles: 768 blocks = 3/CU
  {
    int gy = F / 128;  // 24
    gemm_w1<1 | 2><<<dim3(32 * gy), 512, 0, stream>>>(z2b, w1T, b1, hbuf, M, F, D, gy);
  }
  // h @ W2 + b2 + z2 -> out (fp32)
  {
    int gy = D / 128;  // 6
    gemm_bf16<1 | 4 | 8><<<dim3(64 * gy), 256, 0, stream>>>(hbuf, w2T, b2, z2f,
                                                            out, nullptr, M, D, F, gy, 0);
  }
}